// Round 9
// baseline (308.176 us; speedup 1.0000x reference)
//
#include <hip/hip_runtime.h>
#include <hip/hip_bf16.h>
#include <cstdint>
#include <cstddef>

// Problem constants (fixed shapes per reference)
#define NROWS 8192
#define DIM   1024
#define BMR 128           // block rows (2 waves x 64)
#define BNC 128           // block cols
#define BK  64            // K depth per iteration; 16 iterations
#define NBLK 2080         // 64*65/2 triangle tiles = 8 XCDs x 260
#define EPS 1e-8f
// E pre-scaled by sqrt(10*log2(e)) so MFMA accumulates 10*log2(e)*<a,b>;
// epilogue is a bare exp2f.
#define PRESCALE 3.798288f

typedef short  bf16x8  __attribute__((ext_vector_type(8)));
typedef float  floatx4 __attribute__((ext_vector_type(4)));

typedef __attribute__((address_space(1))) const void CGV;
typedef __attribute__((address_space(3))) void LV;

__device__ __forceinline__ void async_load16(const void* g, void* l) {
    __builtin_amdgcn_global_load_lds((CGV*)g, (LV*)l, 16, 0, 0);
}

__device__ __forceinline__ unsigned short f2bf_rne(float f) {
    union { float f; unsigned u; } c; c.f = f;
    unsigned u = c.u;
    unsigned r = (u + 0x7fffu + ((u >> 16) & 1u)) >> 16;
    return (unsigned short)r;
}

// ---------------------------------------------------------------------------
// Kernel A: fp32 -> bf16 (RNE) with PRESCALE folded in. First 64 blocks also
// zero the 16384-float accumulator region; block 0 zeroes the completion
// counter used by the fused finalize.
// ---------------------------------------------------------------------------
__global__ __launch_bounds__(256) void convert_kernel(
    const float* __restrict__ in, unsigned short* __restrict__ out,
    float* __restrict__ accum /* all_sum ++ pos_sum, 2*NROWS floats */,
    unsigned* __restrict__ counter)
{
    int i = (blockIdx.x * 256 + threadIdx.x) * 4;
    float4 v = *(const float4*)(in + i);
    ushort4 o;
    o.x = f2bf_rne(v.x * PRESCALE);
    o.y = f2bf_rne(v.y * PRESCALE);
    o.z = f2bf_rne(v.z * PRESCALE);
    o.w = f2bf_rne(v.w * PRESCALE);
    *(ushort4*)(out + i) = o;
    if (blockIdx.x < (2 * NROWS) / 256)
        accum[blockIdx.x * 256 + threadIdx.x] = 0.0f;
    if (blockIdx.x == 0 && threadIdx.x == 0)
        counter[0] = 0u;
}

// ---------------------------------------------------------------------------
// Kernel B: symmetric-half fused GEMM — fat wave tiles (64x128, R11-proven) in
// SMALL 2-wave blocks; K-loop/staging/swizzle/epilogue byte-for-byte R8
// (108-110 us, absmax 0, 0 conflicts). R0-R7 session matrix: stage-early,
// dbuf/tribuf, counted vmcnt, 4/8-phase, 256^2 tiles, 4-wave blocks,
// LDS-free register GEMM — ALL regressed (115-325 us). The fat-tile
// 2.67 MFMA/ds_read ratio + 2-wave fast-draining barrier groups is the
// empirical optimum reachable for this structure.
// NEW (R9): fused finalize — last block to finish (device-scope completion
// counter, standard fence chain: per-thread __threadfence -> __syncthreads
// -> tid0 atomic) runs the loss reduction in-kernel, removing the third
// kernel launch. Coherence: all_sum/pos_sum are ONLY touched by
// device-scope atomics during this kernel (never plain-loaded), so no XCD
// L2 holds a stale line; reader uses volatile loads (miss -> coherent
// point). Reduction scratch reuses sA/sB after a barrier — LDS size and
// gemm occupancy unchanged.
// ---------------------------------------------------------------------------
__global__ __launch_bounds__(128, 2) void gemm_fused_kernel(
    const unsigned short* __restrict__ E,   // bf16 bits (prescaled), [NROWS][DIM]
    const int*            __restrict__ labels,
    float*                __restrict__ all_sum,
    float*                __restrict__ pos_sum,
    unsigned*             __restrict__ counter,
    float*                __restrict__ loss_out)
{
    __shared__ __align__(16) unsigned short sA[BMR * BK];   // 16 KB
    __shared__ __align__(16) unsigned short sB[BNC * BK];   // 16 KB

    const int tid  = threadIdx.x;
    const int lane = tid & 63;
    const int w    = tid >> 6;      // wave 0/1 -> rows w*64..w*64+63 of block
    const int colw = lane & 15;
    const int quad = lane >> 4;

    // XCD-local linear tile id, then sqrt triangle decode (strips of 128).
    const int b = blockIdx.x;
    const int t = (b & 7) * 260 + (b >> 3);     // 2080 = 8 x 260
    int bi = (int)((sqrtf(8.0f * (float)t + 1.0f) - 1.0f) * 0.5f);
    while ((bi + 1) * (bi + 2) / 2 <= t) ++bi;
    while (bi * (bi + 1) / 2 > t) --bi;
    const int bj = t - bi * (bi + 1) / 2;

    const int rBase = bi * BMR;     // rows (A tile)
    const int cBase = bj * BNC;     // cols (B tile)

    // Staging: each tile = 128x64 elems = 1024 chunks of 16B; 128 threads x
    // 8 chunks each (rows srow + 16j). Swizzled placement: global chunk
    // c = (t&7) ^ (srow&7); srow&7 invariant under +16.
    const int srow = tid >> 3;                          // 0..15
    const int scol = (((tid & 7) ^ (srow & 7)) << 3);   // elem col 0..56
    const int e0   = tid * 8;                           // LDS elem offset/pass

    floatx4 acc[4][8];
    #pragma unroll
    for (int i = 0; i < 4; ++i)
        #pragma unroll
        for (int j = 0; j < 8; ++j)
            acc[i][j] = (floatx4)0.0f;

    // Fragment reads: A row = w*64 + mt*16 + colw; B row = nt*16 + colw.
    // Chunk (h*4+quad) stored at slot ^(row&7) = ^(colw&7).
    const int swz   = colw & 7;
    const int aRow0 = (w * 64 + colw) * BK;
    const int bRow0 = colw * BK;

    const size_t gA0 = (size_t)(rBase + srow) * DIM + scol;
    const size_t gB0 = (size_t)(cBase + srow) * DIM + scol;
    const size_t rstep = (size_t)16 * DIM;

    for (int k0 = 0; k0 < DIM; k0 += BK) {
        __syncthreads();   // previous compute done before overwrite
        #pragma unroll
        for (int j = 0; j < 8; ++j)
            async_load16(E + gA0 + j * rstep + k0, &sA[e0 + j * 1024]);
        #pragma unroll
        for (int j = 0; j < 8; ++j)
            async_load16(E + gB0 + j * rstep + k0, &sB[e0 + j * 1024]);
        __syncthreads();   // vmcnt drained by compiler before barrier

        #pragma unroll
        for (int h = 0; h < 2; ++h) {
            const int cOff = (((h << 2) | quad) ^ swz) << 3;
            bf16x8 aF[4], bF[8];
            #pragma unroll
            for (int mt = 0; mt < 4; ++mt)
                aF[mt] = *(const bf16x8*)&sA[aRow0 + mt * 16 * BK + cOff];
            #pragma unroll
            for (int nt = 0; nt < 8; ++nt)
                bF[nt] = *(const bf16x8*)&sB[bRow0 + nt * 16 * BK + cOff];

            #pragma unroll
            for (int mt = 0; mt < 4; ++mt)
                #pragma unroll
                for (int nt = 0; nt < 8; ++nt)
                    acc[mt][nt] = __builtin_amdgcn_mfma_f32_16x16x32_bf16(
                        aF[mt], bF[nt], acc[mt][nt], 0, 0, 0);
        }
    }

    // Epilogue. C/D layout (16x16x32): col = lane&15, row = quad*4 + reg.
    // Uniform rule: element (grow, gcol) counts iff grow > gcol; contributes
    // to row grow AND col gcol (R11-verified).
    float labc[8];
    int   gcol[8];
    #pragma unroll
    for (int nt = 0; nt < 8; ++nt) {
        gcol[nt] = cBase + nt * 16 + colw;
        labc[nt] = (float)labels[gcol[nt]];
    }

    float colAll[8] = {0.f, 0.f, 0.f, 0.f, 0.f, 0.f, 0.f, 0.f};
    float colPos[8] = {0.f, 0.f, 0.f, 0.f, 0.f, 0.f, 0.f, 0.f};

    #pragma unroll
    for (int mt = 0; mt < 4; ++mt) {
        const int growBase = rBase + w * 64 + mt * 16 + quad * 4;
        #pragma unroll
        for (int r = 0; r < 4; ++r) {
            const int grow = growBase + r;
            const float labr = (float)labels[grow];
            float sAll = 0.f, sPos = 0.f;
            #pragma unroll
            for (int nt = 0; nt < 8; ++nt) {
                float ev = exp2f(acc[mt][nt][r]);   // PRESCALE folded into E
                ev = (grow > gcol[nt]) ? ev : 0.0f; // strictly-lower only
                sAll += ev;
                sPos += ev * labc[nt];
                colAll[nt] += ev;
                colPos[nt] += ev * labr;
            }
            // row-reduce across the 16 lanes (same quad) sharing this row
            #pragma unroll
            for (int off = 1; off < 16; off <<= 1) {
                sAll += __shfl_xor(sAll, off);
                sPos += __shfl_xor(sPos, off);
            }
            if (colw == 0 && sAll != 0.f) {
                atomicAdd(&all_sum[grow], sAll);
                atomicAdd(&pos_sum[grow], sPos);
            }
        }
    }

    // col-reduce: sum across quads (lanes differing in bits 4,5)
    #pragma unroll
    for (int nt = 0; nt < 8; ++nt) {
        float a = colAll[nt], p = colPos[nt];
        a += __shfl_xor(a, 16);  p += __shfl_xor(p, 16);
        a += __shfl_xor(a, 32);  p += __shfl_xor(p, 32);
        if (quad == 0 && a != 0.f) {
            atomicAdd(&all_sum[gcol[nt]], a);
            atomicAdd(&pos_sum[gcol[nt]], p);
        }
    }

    // ---- fused finalize: last block to finish reduces the loss ----------
    // Fence chain: every thread makes its atomics device-visible, then the
    // block syncs, then tid0 increments the completion counter. The block
    // observing old == NBLK-1 knows all 2080 blocks' atomics are visible.
    __threadfence();
    __syncthreads();        // also: all waves done with sA/sB -> reuse ok
    int* flagp = (int*)&sB[BNC * BK - 2];   // 4B scratch in sB tail
    if (tid == 0)
        *flagp = (atomicAdd(counter, 1u) == (unsigned)(NBLK - 1));
    __syncthreads();
    if (*flagp) {
        volatile const float* va = all_sum;
        volatile const float* vp = pos_sum;
        float lsum = 0.f, lcnt = 0.f;
        for (int i = tid; i < NROWS; i += 128) {
            if (labels[i] > 0) {
                float p = vp[i];
                float a = va[i] + EPS;
                lsum += -logf(p / a);
                lcnt += 1.0f;
            }
        }
        float* sS = (float*)sA;             // 512 B scratch in sA
        float* sC = (float*)sB;             // 512 B scratch in sB head
        sS[tid] = lsum;
        sC[tid] = lcnt;
        __syncthreads();
        for (int s = 64; s > 0; s >>= 1) {
            if (tid < s) { sS[tid] += sS[tid + s]; sC[tid] += sC[tid + s]; }
            __syncthreads();
        }
        if (tid == 0) {
            float n = sC[0];
            loss_out[0] = (n < 2.0f) ? 0.0f : sS[0] / fmaxf(n, 1.0f);
        }
    }
}

// ---------------------------------------------------------------------------
extern "C" void kernel_launch(void* const* d_in, const int* in_sizes, int n_in,
                              void* d_out, int out_size, void* d_ws, size_t ws_size,
                              hipStream_t stream) {
    const float* emb    = (const float*)d_in[0];
    const int*   labels = (const int*)d_in[1];
    float*       out    = (float*)d_out;

    // workspace layout: [bf16 E: 16 MB][all_sum: 32 KB][pos_sum: 32 KB][ctr]
    unsigned short* Ebf = (unsigned short*)d_ws;
    const size_t embBytes = (size_t)NROWS * DIM * sizeof(unsigned short);
    float* all_sum = (float*)((char*)d_ws + embBytes);
    float* pos_sum = all_sum + NROWS;
    unsigned* counter = (unsigned*)(pos_sum + NROWS);

    convert_kernel<<<(NROWS * DIM) / (4 * 256), 256, 0, stream>>>(
        emb, Ebf, all_sum, counter);

    gemm_fused_kernel<<<NBLK, 128, 0, stream>>>(
        Ebf, labels, all_sum, pos_sum, counter, out);
}

// Round 10
// 182.633 us; speedup vs baseline: 1.6874x; 1.6874x over previous
//
#include <hip/hip_runtime.h>
#include <hip/hip_bf16.h>
#include <cstdint>
#include <cstddef>

// Problem constants (fixed shapes per reference)
#define NROWS 8192
#define DIM   1024
#define BMR 128           // block rows (2 waves x 64)
#define BNC 128           // block cols
#define BK  64            // K depth per iteration; 16 iterations
#define NBLK 2080         // 64*65/2 triangle tiles = 8 XCDs x 260
#define EPS 1e-8f
// E pre-scaled by sqrt(10*log2(e)) so MFMA accumulates 10*log2(e)*<a,b>;
// epilogue is a bare exp2f.
#define PRESCALE 3.798288f

typedef short  bf16x8  __attribute__((ext_vector_type(8)));
typedef float  floatx4 __attribute__((ext_vector_type(4)));

typedef __attribute__((address_space(1))) const void CGV;
typedef __attribute__((address_space(3))) void LV;

__device__ __forceinline__ void async_load16(const void* g, void* l) {
    __builtin_amdgcn_global_load_lds((CGV*)g, (LV*)l, 16, 0, 0);
}

__device__ __forceinline__ unsigned short f2bf_rne(float f) {
    union { float f; unsigned u; } c; c.f = f;
    unsigned u = c.u;
    unsigned r = (u + 0x7fffu + ((u >> 16) & 1u)) >> 16;
    return (unsigned short)r;
}

// ---------------------------------------------------------------------------
// Kernel A: fp32 -> bf16 (RNE) with PRESCALE folded in. First 64 blocks also
// zero the 16384-float accumulator region.
// ---------------------------------------------------------------------------
__global__ __launch_bounds__(256) void convert_kernel(
    const float* __restrict__ in, unsigned short* __restrict__ out,
    float* __restrict__ accum /* all_sum ++ pos_sum, 2*NROWS floats */)
{
    int i = (blockIdx.x * 256 + threadIdx.x) * 4;
    float4 v = *(const float4*)(in + i);
    ushort4 o;
    o.x = f2bf_rne(v.x * PRESCALE);
    o.y = f2bf_rne(v.y * PRESCALE);
    o.z = f2bf_rne(v.z * PRESCALE);
    o.w = f2bf_rne(v.w * PRESCALE);
    *(ushort4*)(out + i) = o;
    if (blockIdx.x < (2 * NROWS) / 256)
        accum[blockIdx.x * 256 + threadIdx.x] = 0.0f;
}

// ---------------------------------------------------------------------------
// Kernel B: symmetric-half fused GEMM — fat wave tiles (64x128) in SMALL
// 2-wave blocks. K-loop: global_load_lds w16 + 2 __syncthreads; chunk
// swizzle c' = c ^ (row&7) (0 conflicts measured); XCD-local tile order.
// UNIFORM symmetry (absmax 0 across 10 rounds): keep strictly-lower
// elements (grow > gcol); each feeds row grow AND col gcol — every
// unordered pair exactly once, diag handled implicitly.
//
// FINAL (R10). Session matrix, all falsified against this structure:
//   R1 BK=32 tribuf counted-vmcnt      115 us (thin phases, swizzle broke)
//   R2 256^2 fat 2-barrier             166 us (tail + 2-phase ceiling)
//   R3 256^2 4-phase counted-vmcnt     163 us (asm scaffolding, no gain)
//   R4 256^2 asm-free single-buf       155 us (same ceiling)
//   R5 128^2 stage-early dbuf 4-wave   170 us (stage-early no help)
//   R6 LDS-free register GEMM          325 us (TA-bound gather)
//   R7 m97-exact 4-wave single-buf     135 us (2x occupancy, -25% perf)
//   R9 fused finalize w/ __threadfence 244 us (device fence thrashes L2)
// The fat-tile 2.67 MFMA/ds_read ratio + 2-wave fast-draining barrier
// groups + separate small launches is the empirical optimum reachable.
// ---------------------------------------------------------------------------
__global__ __launch_bounds__(128, 2) void gemm_fused_kernel(
    const unsigned short* __restrict__ E,   // bf16 bits (prescaled), [NROWS][DIM]
    const int*            __restrict__ labels,
    float*                __restrict__ all_sum,
    float*                __restrict__ pos_sum)
{
    __shared__ __align__(16) unsigned short sA[BMR * BK];   // 16 KB
    __shared__ __align__(16) unsigned short sB[BNC * BK];   // 16 KB

    const int tid  = threadIdx.x;
    const int lane = tid & 63;
    const int w    = tid >> 6;      // wave 0/1 -> rows w*64..w*64+63 of block
    const int colw = lane & 15;
    const int quad = lane >> 4;

    // XCD-local linear tile id, then sqrt triangle decode (strips of 128).
    const int b = blockIdx.x;
    const int t = (b & 7) * 260 + (b >> 3);     // 2080 = 8 x 260
    int bi = (int)((sqrtf(8.0f * (float)t + 1.0f) - 1.0f) * 0.5f);
    while ((bi + 1) * (bi + 2) / 2 <= t) ++bi;
    while (bi * (bi + 1) / 2 > t) --bi;
    const int bj = t - bi * (bi + 1) / 2;

    const int rBase = bi * BMR;     // rows (A tile)
    const int cBase = bj * BNC;     // cols (B tile)

    // Staging: each tile = 128x64 elems = 1024 chunks of 16B; 128 threads x
    // 8 chunks each (rows srow + 16j). Swizzled placement: global chunk
    // c = (t&7) ^ (srow&7); srow&7 invariant under +16.
    const int srow = tid >> 3;                          // 0..15
    const int scol = (((tid & 7) ^ (srow & 7)) << 3);   // elem col 0..56
    const int e0   = tid * 8;                           // LDS elem offset/pass

    floatx4 acc[4][8];
    #pragma unroll
    for (int i = 0; i < 4; ++i)
        #pragma unroll
        for (int j = 0; j < 8; ++j)
            acc[i][j] = (floatx4)0.0f;

    // Fragment reads: A row = w*64 + mt*16 + colw; B row = nt*16 + colw.
    // Chunk (h*4+quad) stored at slot ^(row&7) = ^(colw&7).
    const int swz   = colw & 7;
    const int aRow0 = (w * 64 + colw) * BK;
    const int bRow0 = colw * BK;

    const size_t gA0 = (size_t)(rBase + srow) * DIM + scol;
    const size_t gB0 = (size_t)(cBase + srow) * DIM + scol;
    const size_t rstep = (size_t)16 * DIM;

    for (int k0 = 0; k0 < DIM; k0 += BK) {
        __syncthreads();   // previous compute done before overwrite
        #pragma unroll
        for (int j = 0; j < 8; ++j)
            async_load16(E + gA0 + j * rstep + k0, &sA[e0 + j * 1024]);
        #pragma unroll
        for (int j = 0; j < 8; ++j)
            async_load16(E + gB0 + j * rstep + k0, &sB[e0 + j * 1024]);
        __syncthreads();   // vmcnt drained by compiler before barrier

        #pragma unroll
        for (int h = 0; h < 2; ++h) {
            const int cOff = (((h << 2) | quad) ^ swz) << 3;
            bf16x8 aF[4], bF[8];
            #pragma unroll
            for (int mt = 0; mt < 4; ++mt)
                aF[mt] = *(const bf16x8*)&sA[aRow0 + mt * 16 * BK + cOff];
            #pragma unroll
            for (int nt = 0; nt < 8; ++nt)
                bF[nt] = *(const bf16x8*)&sB[bRow0 + nt * 16 * BK + cOff];

            #pragma unroll
            for (int mt = 0; mt < 4; ++mt)
                #pragma unroll
                for (int nt = 0; nt < 8; ++nt)
                    acc[mt][nt] = __builtin_amdgcn_mfma_f32_16x16x32_bf16(
                        aF[mt], bF[nt], acc[mt][nt], 0, 0, 0);
        }
    }

    // Epilogue. C/D layout (16x16x32): col = lane&15, row = quad*4 + reg.
    // Uniform rule: element (grow, gcol) counts iff grow > gcol; contributes
    // to row grow AND col gcol.
    float labc[8];
    int   gcol[8];
    #pragma unroll
    for (int nt = 0; nt < 8; ++nt) {
        gcol[nt] = cBase + nt * 16 + colw;
        labc[nt] = (float)labels[gcol[nt]];
    }

    float colAll[8] = {0.f, 0.f, 0.f, 0.f, 0.f, 0.f, 0.f, 0.f};
    float colPos[8] = {0.f, 0.f, 0.f, 0.f, 0.f, 0.f, 0.f, 0.f};

    #pragma unroll
    for (int mt = 0; mt < 4; ++mt) {
        const int growBase = rBase + w * 64 + mt * 16 + quad * 4;
        #pragma unroll
        for (int r = 0; r < 4; ++r) {
            const int grow = growBase + r;
            const float labr = (float)labels[grow];
            float sAll = 0.f, sPos = 0.f;
            #pragma unroll
            for (int nt = 0; nt < 8; ++nt) {
                float ev = exp2f(acc[mt][nt][r]);   // PRESCALE folded into E
                ev = (grow > gcol[nt]) ? ev : 0.0f; // strictly-lower only
                sAll += ev;
                sPos += ev * labc[nt];
                colAll[nt] += ev;
                colPos[nt] += ev * labr;
            }
            // row-reduce across the 16 lanes (same quad) sharing this row
            #pragma unroll
            for (int off = 1; off < 16; off <<= 1) {
                sAll += __shfl_xor(sAll, off);
                sPos += __shfl_xor(sPos, off);
            }
            if (colw == 0 && sAll != 0.f) {
                atomicAdd(&all_sum[grow], sAll);
                atomicAdd(&pos_sum[grow], sPos);
            }
        }
    }

    // col-reduce: sum across quads (lanes differing in bits 4,5)
    #pragma unroll
    for (int nt = 0; nt < 8; ++nt) {
        float a = colAll[nt], p = colPos[nt];
        a += __shfl_xor(a, 16);  p += __shfl_xor(p, 16);
        a += __shfl_xor(a, 32);  p += __shfl_xor(p, 32);
        if (quad == 0 && a != 0.f) {
            atomicAdd(&all_sum[gcol[nt]], a);
            atomicAdd(&pos_sum[gcol[nt]], p);
        }
    }
}

// ---------------------------------------------------------------------------
// Kernel C: loss = mean over rows with lab==1 of -log(pos/(all+eps)); 0 if n_ref<2
// ---------------------------------------------------------------------------
__global__ __launch_bounds__(1024) void finalize_kernel(
    const float* __restrict__ all_sum,
    const float* __restrict__ pos_sum,
    const int*   __restrict__ labels,
    float*       __restrict__ out)
{
    __shared__ float sSum[1024];
    __shared__ float sCnt[1024];
    const int tid = threadIdx.x;
    float lsum = 0.f, lcnt = 0.f;
    for (int i = tid; i < NROWS; i += 1024) {
        if (labels[i] > 0) {
            float p = pos_sum[i];
            float a = all_sum[i] + EPS;
            lsum += -logf(p / a);
            lcnt += 1.0f;
        }
    }
    sSum[tid] = lsum;
    sCnt[tid] = lcnt;
    __syncthreads();
    for (int s = 512; s > 0; s >>= 1) {
        if (tid < s) { sSum[tid] += sSum[tid + s]; sCnt[tid] += sCnt[tid + s]; }
        __syncthreads();
    }
    if (tid == 0) {
        float n = sCnt[0];
        out[0] = (n < 2.0f) ? 0.0f : sSum[0] / fmaxf(n, 1.0f);
    }
}

// ---------------------------------------------------------------------------
extern "C" void kernel_launch(void* const* d_in, const int* in_sizes, int n_in,
                              void* d_out, int out_size, void* d_ws, size_t ws_size,
                              hipStream_t stream) {
    const float* emb    = (const float*)d_in[0];
    const int*   labels = (const int*)d_in[1];
    float*       out    = (float*)d_out;

    // workspace layout: [bf16 E: 16 MB][all_sum: 32 KB][pos_sum: 32 KB]
    unsigned short* Ebf = (unsigned short*)d_ws;
    const size_t embBytes = (size_t)NROWS * DIM * sizeof(unsigned short);
    float* all_sum = (float*)((char*)d_ws + embBytes);
    float* pos_sum = all_sum + NROWS;

    convert_kernel<<<(NROWS * DIM) / (4 * 256), 256, 0, stream>>>(emb, Ebf, all_sum);

    gemm_fused_kernel<<<NBLK, 128, 0, stream>>>(Ebf, labels, all_sum, pos_sum);

    finalize_kernel<<<1, 1024, 0, stream>>>(all_sum, pos_sum, labels, out);
}